// Round 9
// baseline (865.540 us; speedup 1.0000x reference)
//
#include <hip/hip_runtime.h>
#include <hip/hip_fp16.h>
#include <cstdint>
#include <cstddef>

#define B_    256
#define T_    128
#define SIG_  64
#define MET_  32
#define H_    256
#define F_    16
#define NCOL  1040   // X cols: [i:0..255 | ste:256..511 | c:512..767 | o:768..1023 | fre:1024..1039]

// R20: recur_kernel remains BYTE-EXACT R13 (565 us, verified across
// R17/R18/R19). FROZEN — R14/R15/R16 each spilled from "harmless" edits.
// proj reverted to the R18 configuration (128x128 tile, 4 blocks/CU —
// verified 787.5 total; R19's 256-row tile cost 55 us via occupancy).
// R20 change: proj reads W/bias DIRECTLY from the original input arrays
// (each 128-col tile sits inside one 256-col section; k-tiles split at the
// sig/met boundary, so the source select is block/k0-uniform). Wcat/bcat
// are deleted; pack shrinks to U8/UF conversion only.
#define NLDS  9
#define NREG  20
#define NSTR0 (NLDS + NREG)   // 29 -> 3 streamed slots (48 KB/step/CU)

__device__ __forceinline__ float hsig(float x) {
    return fminf(fmaxf(x * (1.0f/6.0f) + 0.5f, 0.0f), 1.0f);
}

__device__ __forceinline__ unsigned short f2h(float f) {
    __half h = __float2half(f);
    return *(unsigned short*)&h;
}

__device__ __forceinline__ float ntload_f(const float* p) {
    return __builtin_nontemporal_load(p);
}
__device__ __forceinline__ float4 ntload_f4(const float* p) {
    float4 v;
    v.x = __builtin_nontemporal_load(p + 0);
    v.y = __builtin_nontemporal_load(p + 1);
    v.z = __builtin_nontemporal_load(p + 2);
    v.w = __builtin_nontemporal_load(p + 3);
    return v;
}

// Workgroup barrier WITHOUT the vmcnt(0) drain __syncthreads() forces.
// lgkmcnt(0) makes all LDS ops complete before s_barrier (sufficient for
// intra-block LDS coherence). Pending GLOBAL loads stay in flight across
// the barrier — safe: streamed U values are step-invariant.
__device__ __forceinline__ void lbar() {
    asm volatile("s_waitcnt lgkmcnt(0)\n\ts_barrier" ::: "memory");
}

typedef _Float16 half2v __attribute__((ext_vector_type(2)));

__device__ __forceinline__ float dot2(unsigned int u, unsigned int h, float acc) {
#if __has_builtin(__builtin_amdgcn_fdot2)
    return __builtin_amdgcn_fdot2(__builtin_bit_cast(half2v, u),
                                  __builtin_bit_cast(half2v, h), acc, false);
#else
    __half2 uu = *(__half2*)&u, hh = *(__half2*)&h;
    float2 uf = __half22float2(uu), hf = __half22float2(hh);
    return fmaf(uf.x, hf.x, fmaf(uf.y, hf.y, acc));
#endif
}

__device__ __forceinline__ float dot2x4(uint4 u, uint4 h, float acc) {
    acc = dot2(u.x, h.x, acc);
    acc = dot2(u.y, h.y, acc);
    acc = dot2(u.z, h.z, acc);
    acc = dot2(u.w, h.w, acc);
    return acc;
}

// ---------------------------------------------------------------------------
// Pack (R20: U8/UF only — Wcat/bcat deleted, proj reads inputs directly):
// U8: fp16 main cols, [k8][col] uint4 — slot kk at U8[kk*1024+col] holds
//     k=8kk..8kk+7 of col. UF: fp16 fre cols, [col][k] (8 KB, L1-resident).
// ---------------------------------------------------------------------------
__global__ __launch_bounds__(256) void pack_kernel(
    const float* __restrict__ Ui, const float* __restrict__ Uste, const float* __restrict__ Ufre,
    const float* __restrict__ Uc, const float* __restrict__ Uo,
    unsigned short* __restrict__ U8, unsigned short* __restrict__ UF)
{
    int gtid = blockIdx.x * blockDim.x + threadIdx.x;
    int stride = gridDim.x * blockDim.x;
    const float* Us[4] = {Ui, Uste, Uc, Uo};

    // main 1024 cols
    for (int i = gtid; i < 1024*H_; i += stride) {
        int col = i >> 8, k = i & 255;
        int sec = col >> 8, idx = col & 255;
        U8[(((k >> 3) * 1024) + col) * 8 + (k & 7)] = f2h(Us[sec][k*H_ + idx]);
    }
    // fre 16 cols
    for (int i = gtid; i < 16*H_; i += stride) {
        int col = i >> 8, k = i & 255;
        UF[col*H_ + k] = f2h(Ufre[k*F_ + col]);
    }
}

// ---------------------------------------------------------------------------
// Phase 1: input projection GEMM for ALL time steps.
// R17: coalesced float4 A-staging. R18: float4 W staging, float4 X stores
// with fused bias, 4 blocks/CU (verified config). R20: W/bias read directly
// from original arrays — per-block section sec = c0b>>8 (tile fits in one
// section), per-k0 sig/met select (k0<64 -> sig rows, k0=64 -> met rows).
// ---------------------------------------------------------------------------
__global__ __launch_bounds__(256, 4) void proj_kernel(
    const float* __restrict__ sig, const float* __restrict__ met,
    const float* __restrict__ Wis, const float* __restrict__ Wstes, const float* __restrict__ Wcs,
    const float* __restrict__ Wos, const float* __restrict__ Wfres,
    const float* __restrict__ Wim, const float* __restrict__ Wstem, const float* __restrict__ Wcm,
    const float* __restrict__ Wom, const float* __restrict__ Wfrem,
    const float* __restrict__ bi, const float* __restrict__ bste, const float* __restrict__ bc,
    const float* __restrict__ bo, const float* __restrict__ bfre,
    float* __restrict__ X)
{
    __shared__ float A_s[32][132];
    __shared__ float W_s[32][128];
    int tid = threadIdx.x;
    int c0b = blockIdx.x * 128;
    int m0  = blockIdx.y * 128;
    int t0  = blockIdx.z * 16;
    int r0  = (tid >> 4) * 8;
    int c0t = (tid & 15) * 8;

    // block-uniform section: X col layout [i|ste|c|o|fre]
    int sec = c0b >> 8;                  // 0..4 (4 = fre, tile c0b=1024)
    int cidx = c0b & 255;                // col offset within section (0 or 128)
    const float* WsigA[5] = {Wis, Wstes, Wcs, Wos, Wfres};
    const float* WmetA[5] = {Wim, Wstem, Wcm, Wom, Wfrem};
    const float* bsA[5]   = {bi, bste, bc, bo, bfre};

    float acc[8][8];
    #pragma unroll
    for (int i = 0; i < 8; ++i)
        #pragma unroll
        for (int j = 0; j < 8; ++j) acc[i][j] = 0.0f;

    for (int k0 = 0; k0 < 96; k0 += 32) {
        // A tile: 32(k) x 128(m) = 1024 float4 loads, 4 per thread.
        #pragma unroll
        for (int p = 0; p < 4; ++p) {
            int f4 = tid + p * 256;
            int kq = f4 & 7;
            int ml = f4 >> 3;
            int m  = m0 + ml;
            int bb = m >> 4, tl = m & 15;
            int g  = bb * T_ + t0 + tl;
            float4 v;
            if (k0 < 64) v = *(const float4*)&sig[(size_t)g * SIG_ + k0 + 4*kq];
            else         v = *(const float4*)&met[(size_t)g * MET_ + 4*kq];
            A_s[4*kq+0][ml] = v.x;
            A_s[4*kq+1][ml] = v.y;
            A_s[4*kq+2][ml] = v.z;
            A_s[4*kq+3][ml] = v.w;
        }
        // W tile from ORIGINAL arrays. k-rows this k0: sig rows k0..k0+31
        // (k0<64) or met rows 0..31 (k0=64) — uniform per k0. Section
        // uniform per block. Same per-lane addresses/coalescing as the
        // packed Wcat path.
        {
            const float* Wsrc;
            int rstride;
            if (sec < 4) { Wsrc = (k0 < 64) ? (WsigA[sec] + (size_t)k0 * H_) : WmetA[sec]; rstride = H_; }
            else         { Wsrc = (k0 < 64) ? (Wfres + (size_t)k0 * F_)      : Wfrem;      rstride = F_; }
            #pragma unroll
            for (int p = 0; p < 4; ++p) {
                int idx = tid + p * 256;
                int kk  = idx >> 5;
                int c4  = (idx & 31) * 4;
                float4 w;
                if (sec < 4) {
                    w = *(const float4*)&Wsrc[(size_t)kk * rstride + cidx + c4];
                } else if (c4 + 3 < F_) {
                    w = *(const float4*)&Wsrc[(size_t)kk * rstride + c4];
                } else {
                    w.x = w.y = w.z = w.w = 0.0f;
                }
                *(float4*)&W_s[kk][c4] = w;
            }
        }
        __syncthreads();
        #pragma unroll
        for (int kk = 0; kk < 32; ++kk) {
            float4 a0 = *(const float4*)&A_s[kk][r0];
            float4 a1 = *(const float4*)&A_s[kk][r0+4];
            float4 w0 = *(const float4*)&W_s[kk][c0t];
            float4 w1 = *(const float4*)&W_s[kk][c0t+4];
            float av[8] = {a0.x,a0.y,a0.z,a0.w,a1.x,a1.y,a1.z,a1.w};
            float wv[8] = {w0.x,w0.y,w0.z,w0.w,w1.x,w1.y,w1.z,w1.w};
            #pragma unroll
            for (int i = 0; i < 8; ++i)
                #pragma unroll
                for (int j = 0; j < 8; ++j)
                    acc[i][j] = fmaf(av[i], wv[j], acc[i][j]);
        }
        __syncthreads();
    }
    // Epilogue: two float4 stores per row with fused bias from the original
    // bias array (section-uniform). Validity uniform per 8-col group.
    int n0 = c0b + c0t;
    if (n0 < NCOL) {
        const float* bsrc = bsA[sec];
        int bidx = (sec < 4) ? (n0 & 255) : (n0 - 1024);
        float4 b0 = *(const float4*)&bsrc[bidx];
        float4 b1 = *(const float4*)&bsrc[bidx + 4];
        #pragma unroll
        for (int i = 0; i < 8; ++i) {
            int m = m0 + r0 + i;
            int bb = m >> 4, tl = m & 15;
            size_t row = (size_t)bb * T_ + t0 + tl;
            float4 v0, v1;
            v0.x = acc[i][0] + b0.x; v0.y = acc[i][1] + b0.y;
            v0.z = acc[i][2] + b0.z; v0.w = acc[i][3] + b0.w;
            v1.x = acc[i][4] + b1.x; v1.y = acc[i][5] + b1.y;
            v1.z = acc[i][6] + b1.z; v1.w = acc[i][7] + b1.w;
            *(float4*)&X[row*NCOL + n0]     = v0;
            *(float4*)&X[row*NCOL + n0 + 4] = v1;
        }
    }
}

// ---------------------------------------------------------------------------
// Phase 2: full recurrence, SINGLE launch, grid=256 x 512 threads.
// BYTE-EXACT R13 (565 us verified). Do not edit — see header comment.
// ---------------------------------------------------------------------------
__global__ __launch_bounds__(512, 2) void recur_kernel(
    const float* __restrict__ X, const uint4* __restrict__ U8,
    const uint4* __restrict__ UF,
    const float* __restrict__ U_a, const float* __restrict__ b_a,
    const float* __restrict__ W_p, const float* __restrict__ b_p,
    const float* __restrict__ fc_w, const float* __restrict__ fc_b,
    float* __restrict__ out)
{
    __shared__ uint4 ldsU[NLDS * 1024];  // 147,456 B
    __shared__ float pre_s[1024];        //   4,096 B
    __shared__ uint4 h_p4[H_/8];         //     512 B (h as fp16 pairs)
    __shared__ float qp[64];             //     256 B (fre quarter partials: [fcol][q])
    __shared__ float cs_s[16], sn_s[16]; //     128 B   (total ~152.4 KB)

    int tid  = threadIdx.x;
    int b    = blockIdx.x;
    int lane = tid & 63;
    int wid  = tid >> 6;                 // 0..7

    int c0 = tid;                        // column pair owned by this thread
    int c1 = tid + 512;

    // fre ownership: designated lanes (lane&7)==7, 8 per wave.
    // lane -> quarter q = lane>>4 (0..3), colsel = (lane>>3)&1;
    // fre col fcol = wid + 8*colsel (0..15).
    bool isfre = ((lane & 7) == 7);
    int fq     = lane >> 4;
    int fcol   = wid + 8 * ((lane >> 3) & 1);

    // update-phase ownership: j = tid>>1 (h row), f0 = (tid&1)*8 (8 freqs)
    int j     = tid >> 1;
    int fhalf = tid & 1;
    int f0    = fhalf * 8;

    // stage LDS U tier (slots 0..NLDS-1)
    for (int i = tid; i < NLDS * 1024; i += 512)
        ldsU[i] = U8[i];

    // persistent register U tier (slots NLDS..NLDS+NREG-1), loaded once.
    // Fully-static indexing only (rule #20).
    uint4 ur0[NREG], ur1[NREG];
    #pragma unroll
    for (int r = 0; r < NREG; ++r) {
        ur0[r] = U8[(NLDS + r) * 1024 + c0];
        ur1[r] = U8[(NLDS + r) * 1024 + c1];
    }

    if (tid < H_/8) { uint4 z; z.x=z.y=z.z=z.w=0u; h_p4[tid] = z; }
    if (tid < 16) {
        float ang = (float)tid * 0.39269908169872414f; // 2*pi/16
        cs_s[tid] = cosf(ang);
        sn_s[tid] = sinf(ang);
    }
    float Sre[8], Sim[8];
    #pragma unroll
    for (int r = 0; r < 8; ++r) { Sre[r] = 0.0f; Sim[r] = 0.0f; }

    float ba_j = b_a[j];
    float4 ua4a = ((const float4*)U_a)[fhalf * 2 + 0];
    float4 ua4b = ((const float4*)U_a)[fhalf * 2 + 1];
    const uint4* UFq = UF + (fcol * 32 + fq * 8);   // quarter fq of fre col fcol
    const float* Xb = X + (size_t)b * T_ * NCOL;
    __half* h_h = (__half*)h_p4;

    float hnew = 0.0f;
    __syncthreads();

    for (int t = 0; t < T_; ++t) {
        const float* xrow = Xb + (size_t)t * NCOL;

        // ---- dot phase: pre[c] = x[c] + U[:,c] . h for c in {c0, c1} ----
        float a0 = ntload_f(&xrow[c0]);
        float a1 = ntload_f(&xrow[c1]);
        // streamed tier (slots NSTR0..31): loads pipeline across lbar()
        #pragma unroll
        for (int kk = NSTR0; kk < 32; ++kk) {
            uint4 u0 = U8[kk * 1024 + c0];
            uint4 u1 = U8[kk * 1024 + c1];
            uint4 hh = h_p4[kk];
            a0 = dot2x4(u0, hh, a0);
            a1 = dot2x4(u1, hh, a1);
        }
        // register tier (slots NLDS..NSTR0-1)
        #pragma unroll
        for (int r = 0; r < NREG; ++r) {
            uint4 hh = h_p4[NLDS + r];
            a0 = dot2x4(ur0[r], hh, a0);
            a1 = dot2x4(ur1[r], hh, a1);
        }
        // LDS tier (slots 0..NLDS-1); h_p4 reads are broadcasts
        #pragma unroll
        for (int d = 0; d < NLDS; ++d) {
            uint4 u0 = ldsU[d * 1024 + c0];
            uint4 u1 = ldsU[d * 1024 + c1];
            uint4 hh = h_p4[d];
            a0 = dot2x4(u0, hh, a0);
            a1 = dot2x4(u1, hh, a1);
        }
        float fa = 0.0f;
        if (isfre) {
            #pragma unroll
            for (int s = 0; s < 8; ++s)
                fa = dot2x4(UFq[s], h_p4[fq * 8 + s], fa);
        }
        pre_s[c0] = a0;
        pre_s[c1] = a1;
        if (isfre) qp[fcol * 4 + fq] = fa;
        lbar();   // A: pre_s + qp visible; h_p4 reads done (lgkm only)

        // ---- update phase ----
        float xi   = pre_s[j];
        float xste = pre_s[256 + j];
        float xc   = pre_s[512 + j];
        float xo   = pre_s[768 + j];
        float gi   = hsig(xi);
        float gste = hsig(xste);
        float go   = hsig(xo);
        float cc   = gi * tanhf(xc);

        float4 xfa = ntload_f4(&xrow[1024 + f0]);
        float4 xfb = ntload_f4(&xrow[1024 + f0 + 4]);
        float xfre[8] = {xfa.x, xfa.y, xfa.z, xfa.w, xfb.x, xfb.y, xfb.z, xfb.w};
        float fre[8];
        #pragma unroll
        for (int r = 0; r < 8; ++r) {
            float4 q = *(const float4*)&qp[(f0 + r) * 4];
            fre[r] = hsig(xfre[r] + q.x + q.y + q.z + q.w);
        }

        int tt1 = (t + 1) & 15;
        float ua[8] = {ua4a.x, ua4a.y, ua4a.z, ua4a.w, ua4b.x, ua4b.y, ua4b.z, ua4b.w};
        float Aa = 0.0f;
        #pragma unroll
        for (int r = 0; r < 8; ++r) {
            int idx = (tt1 * (f0 + r)) & 15;
            float dec = gste * fre[r];
            float sre = fmaf(dec, Sre[r], cc * cs_s[idx]);
            float sim = fmaf(dec, Sim[r], cc * sn_s[idx]);
            Sre[r] = sre; Sim[r] = sim;
            Aa = fmaf(fmaf(sre, sre, sim*sim), ua[r], Aa);
        }
        Aa += __shfl_xor(Aa, 1);   // pair (fhalf 0/1) -> full 16-f sum
        float a = tanhf(Aa + ba_j);
        hnew = go * a;
        if (fhalf == 0) h_h[j] = __float2half(hnew);
        lbar();   // B: h visible for next step (lgkm only)
    }

    // ---- head: out[b] = (sum_j h[j]*W_p[j] + b_p)*fc_w + fc_b ----
    if (fhalf == 0) pre_s[j] = hnew * W_p[j];
    __syncthreads();
    for (int s = 128; s > 0; s >>= 1) {
        if (tid < s) pre_s[tid] += pre_s[tid + s];
        __syncthreads();
    }
    if (tid == 0) out[b] = (pre_s[0] + b_p[0]) * fc_w[0] + fc_b[0];
}

// ---------------------------------------------------------------------------
extern "C" void kernel_launch(void* const* d_in, const int* in_sizes, int n_in,
                              void* d_out, int out_size, void* d_ws, size_t ws_size,
                              hipStream_t stream) {
    const float* signal = (const float*)d_in[0];
    const float* metmast = (const float*)d_in[1];
    const float* W_i_s   = (const float*)d_in[2];
    const float* W_ste_s = (const float*)d_in[3];
    const float* W_fre_s = (const float*)d_in[4];
    const float* W_c_s   = (const float*)d_in[5];
    const float* W_o_s   = (const float*)d_in[6];
    const float* W_i_m   = (const float*)d_in[7];
    const float* W_ste_m = (const float*)d_in[8];
    const float* W_fre_m = (const float*)d_in[9];
    const float* W_c_m   = (const float*)d_in[10];
    const float* W_o_m   = (const float*)d_in[11];
    const float* U_i   = (const float*)d_in[12];
    const float* b_i   = (const float*)d_in[13];
    const float* U_ste = (const float*)d_in[14];
    const float* b_ste = (const float*)d_in[15];
    const float* U_fre = (const float*)d_in[16];
    const float* b_fre = (const float*)d_in[17];
    const float* U_c   = (const float*)d_in[18];
    const float* b_c   = (const float*)d_in[19];
    const float* U_o   = (const float*)d_in[20];
    const float* b_o   = (const float*)d_in[21];
    const float* U_a   = (const float*)d_in[22];
    const float* b_a   = (const float*)d_in[23];
    const float* W_p   = (const float*)d_in[24];
    const float* b_p   = (const float*)d_in[25];
    const float* fc_w  = (const float*)d_in[26];
    const float* fc_b  = (const float*)d_in[27];
    float* out = (float*)d_out;

    char* ws = (char*)d_ws;
    unsigned short* U8 = (unsigned short*)(ws + 0);        // 1024*256*2 = 524288
    unsigned short* UF = (unsigned short*)(ws + 524288);   // 16*256*2 = 8192 -> 532480
    float*          X  = (float*)(ws + 532480);            // 256*128*1040*4 = 136314880
    // total ~136.9 MB

    pack_kernel<<<256, 256, 0, stream>>>(U_i, U_ste, U_fre, U_c, U_o, U8, UF);

    proj_kernel<<<dim3(9, 32, 8), 256, 0, stream>>>(
        signal, metmast,
        W_i_s, W_ste_s, W_c_s, W_o_s, W_fre_s,
        W_i_m, W_ste_m, W_c_m, W_o_m, W_fre_m,
        b_i, b_ste, b_c, b_o, b_fre,
        X);

    recur_kernel<<<B_, 512, 0, stream>>>(X, (const uint4*)U8, (const uint4*)UF,
                                         U_a, b_a, W_p, b_p, fc_w, fc_b, out);
}

// Round 10
// 781.030 us; speedup vs baseline: 1.1082x; 1.1082x over previous
//
#include <hip/hip_runtime.h>
#include <hip/hip_fp16.h>
#include <cstdint>
#include <cstddef>

#define B_    256
#define T_    128
#define SIG_  64
#define MET_  32
#define H_    256
#define F_    16
#define NCOL  1040   // X cols: [i:0..255 | ste:256..511 | c:512..767 | o:768..1023 | fre:1024..1039]

// R21 = BYTE-EXACT R18 restore (787.5 us, best verified).
// recur_kernel is BYTE-EXACT R13 (565 us) — FROZEN: R14/R15/R16 each
// spilled per-step scratch from "harmless" edits (regalloc knife-edge at
// 128 VGPR + AGPR tier). proj is the R17/R18 verified config: coalesced
// float4 A-staging, float4 W staging, float4 X stores with fused bias,
// 4 blocks/CU. R19 (256-row tile, -55us) and R20 (direct-W read, -78us)
// both regressed and are reverted.
#define NLDS  9
#define NREG  20
#define NSTR0 (NLDS + NREG)   // 29 -> 3 streamed slots (48 KB/step/CU)

__device__ __forceinline__ float hsig(float x) {
    return fminf(fmaxf(x * (1.0f/6.0f) + 0.5f, 0.0f), 1.0f);
}

__device__ __forceinline__ unsigned short f2h(float f) {
    __half h = __float2half(f);
    return *(unsigned short*)&h;
}

__device__ __forceinline__ float ntload_f(const float* p) {
    return __builtin_nontemporal_load(p);
}
__device__ __forceinline__ float4 ntload_f4(const float* p) {
    float4 v;
    v.x = __builtin_nontemporal_load(p + 0);
    v.y = __builtin_nontemporal_load(p + 1);
    v.z = __builtin_nontemporal_load(p + 2);
    v.w = __builtin_nontemporal_load(p + 3);
    return v;
}

// Workgroup barrier WITHOUT the vmcnt(0) drain __syncthreads() forces.
// lgkmcnt(0) makes all LDS ops complete before s_barrier (sufficient for
// intra-block LDS coherence). Pending GLOBAL loads stay in flight across
// the barrier — safe: streamed U values are step-invariant.
__device__ __forceinline__ void lbar() {
    asm volatile("s_waitcnt lgkmcnt(0)\n\ts_barrier" ::: "memory");
}

typedef _Float16 half2v __attribute__((ext_vector_type(2)));

__device__ __forceinline__ float dot2(unsigned int u, unsigned int h, float acc) {
#if __has_builtin(__builtin_amdgcn_fdot2)
    return __builtin_amdgcn_fdot2(__builtin_bit_cast(half2v, u),
                                  __builtin_bit_cast(half2v, h), acc, false);
#else
    __half2 uu = *(__half2*)&u, hh = *(__half2*)&h;
    float2 uf = __half22float2(uu), hf = __half22float2(hh);
    return fmaf(uf.x, hf.x, fmaf(uf.y, hf.y, acc));
#endif
}

__device__ __forceinline__ float dot2x4(uint4 u, uint4 h, float acc) {
    acc = dot2(u.x, h.x, acc);
    acc = dot2(u.y, h.y, acc);
    acc = dot2(u.z, h.z, acc);
    acc = dot2(u.w, h.w, acc);
    return acc;
}

// ---------------------------------------------------------------------------
// Pack: Wcat[96][1040] f32, bcat[1040] f32,
// U8: fp16 main cols, [k8][col] uint4 — slot kk at U8[kk*1024+col] holds
//     k=8kk..8kk+7 of col. UF: fp16 fre cols, [col][k] (8 KB, L1-resident).
// ---------------------------------------------------------------------------
__global__ __launch_bounds__(256) void pack_kernel(
    const float* __restrict__ Wis, const float* __restrict__ Wstes, const float* __restrict__ Wfres,
    const float* __restrict__ Wcs, const float* __restrict__ Wos,
    const float* __restrict__ Wim, const float* __restrict__ Wstem, const float* __restrict__ Wfrem,
    const float* __restrict__ Wcm, const float* __restrict__ Wom,
    const float* __restrict__ Ui, const float* __restrict__ Uste, const float* __restrict__ Ufre,
    const float* __restrict__ Uc, const float* __restrict__ Uo,
    const float* __restrict__ bi, const float* __restrict__ bste, const float* __restrict__ bfre,
    const float* __restrict__ bc, const float* __restrict__ bo,
    float* __restrict__ Wcat, float* __restrict__ bcat,
    unsigned short* __restrict__ U8, unsigned short* __restrict__ UF)
{
    int gtid = blockIdx.x * blockDim.x + threadIdx.x;
    int stride = gridDim.x * blockDim.x;
    const float* Wsig[5] = {Wis, Wstes, Wcs, Wos, Wfres};
    const float* Wmet[5] = {Wim, Wstem, Wcm, Wom, Wfrem};
    const float* Us[4]   = {Ui, Uste, Uc, Uo};
    const float* bs[5]   = {bi, bste, bc, bo, bfre};

    for (int i = gtid; i < 96*NCOL; i += stride) {
        int k = i / NCOL, n = i - k*NCOL;
        int sec, idx, secN;
        if (n < 1024) { sec = n >> 8; idx = n & 255; secN = H_; }
        else          { sec = 4; idx = n - 1024; secN = F_; }
        float v = (k < 64) ? Wsig[sec][k*secN + idx] : Wmet[sec][(k-64)*secN + idx];
        Wcat[k*NCOL + n] = v;
    }
    for (int n = gtid; n < NCOL; n += stride) {
        int sec, idx;
        if (n < 1024) { sec = n >> 8; idx = n & 255; }
        else          { sec = 4; idx = n - 1024; }
        bcat[n] = bs[sec][idx];
    }
    // main 1024 cols
    for (int i = gtid; i < 1024*H_; i += stride) {
        int col = i >> 8, k = i & 255;
        int sec = col >> 8, idx = col & 255;
        U8[(((k >> 3) * 1024) + col) * 8 + (k & 7)] = f2h(Us[sec][k*H_ + idx]);
    }
    // fre 16 cols
    for (int i = gtid; i < 16*H_; i += stride) {
        int col = i >> 8, k = i & 255;
        UF[col*H_ + k] = f2h(Ufre[k*F_ + col]);
    }
}

// ---------------------------------------------------------------------------
// Phase 1: input projection GEMM for ALL time steps.
// R17: coalesced float4 A-staging (lane-fast k, A_s [k][m] +4 pad).
// R18: float4 W staging; float4 X stores with fused float4 bias; uniform
// per-8-col validity check (1040 and the c0t grid make each 8-col group
// all-valid or all-invalid); __launch_bounds__(256,4).
// ---------------------------------------------------------------------------
__global__ __launch_bounds__(256, 4) void proj_kernel(
    const float* __restrict__ sig, const float* __restrict__ met,
    const float* __restrict__ Wcat, const float* __restrict__ bcat,
    float* __restrict__ X)
{
    __shared__ float A_s[32][132];
    __shared__ float W_s[32][128];
    int tid = threadIdx.x;
    int c0b = blockIdx.x * 128;
    int m0  = blockIdx.y * 128;
    int t0  = blockIdx.z * 16;
    int r0  = (tid >> 4) * 8;
    int c0t = (tid & 15) * 8;

    float acc[8][8];
    #pragma unroll
    for (int i = 0; i < 8; ++i)
        #pragma unroll
        for (int j = 0; j < 8; ++j) acc[i][j] = 0.0f;

    for (int k0 = 0; k0 < 96; k0 += 32) {
        // A tile: 32(k) x 128(m) = 1024 float4 loads, 4 per thread.
        // f4 = tid + 256*p; kq = f4 & 7 (k-quad), ml = f4 >> 3 (m-local).
        // Consecutive lanes -> consecutive kq -> contiguous 32-float rows.
        #pragma unroll
        for (int p = 0; p < 4; ++p) {
            int f4 = tid + p * 256;
            int kq = f4 & 7;
            int ml = f4 >> 3;
            int m  = m0 + ml;
            int bb = m >> 4, tl = m & 15;
            int g  = bb * T_ + t0 + tl;
            float4 v;
            if (k0 < 64) v = *(const float4*)&sig[(size_t)g * SIG_ + k0 + 4*kq];
            else         v = *(const float4*)&met[(size_t)g * MET_ + 4*kq];
            A_s[4*kq+0][ml] = v.x;
            A_s[4*kq+1][ml] = v.y;
            A_s[4*kq+2][ml] = v.z;
            A_s[4*kq+3][ml] = v.w;
        }
        // W tile: 32(k) x 128(c) = 1024 float4 slots, 4 per thread.
        // Lanes -> consecutive c4 -> coalesced 16B/lane loads, b128 LDS
        // writes at 16B stride (conflict-free).
        #pragma unroll
        for (int p = 0; p < 4; ++p) {
            int idx = tid + p * 256;
            int kk  = idx >> 5;
            int c4  = (idx & 31) * 4;
            int n   = c0b + c4;
            float4 w;
            if (n + 3 < NCOL) w = *(const float4*)&Wcat[(size_t)(k0+kk)*NCOL + n];
            else { w.x = w.y = w.z = w.w = 0.0f; }
            *(float4*)&W_s[kk][c4] = w;
        }
        __syncthreads();
        #pragma unroll
        for (int kk = 0; kk < 32; ++kk) {
            float4 a0 = *(const float4*)&A_s[kk][r0];
            float4 a1 = *(const float4*)&A_s[kk][r0+4];
            float4 w0 = *(const float4*)&W_s[kk][c0t];
            float4 w1 = *(const float4*)&W_s[kk][c0t+4];
            float av[8] = {a0.x,a0.y,a0.z,a0.w,a1.x,a1.y,a1.z,a1.w};
            float wv[8] = {w0.x,w0.y,w0.z,w0.w,w1.x,w1.y,w1.z,w1.w};
            #pragma unroll
            for (int i = 0; i < 8; ++i)
                #pragma unroll
                for (int j = 0; j < 8; ++j)
                    acc[i][j] = fmaf(av[i], wv[j], acc[i][j]);
        }
        __syncthreads();
    }
    // Epilogue: two float4 stores per row (fused float4 bias). Validity is
    // uniform per 8-col group: n0 = c0b + c0t; group fully valid iff
    // n0 < NCOL (1040 = 1024+16 aligns with the 8-col grid).
    int n0 = c0b + c0t;
    if (n0 < NCOL) {
        float4 b0 = *(const float4*)&bcat[n0];
        float4 b1 = *(const float4*)&bcat[n0 + 4];
        #pragma unroll
        for (int i = 0; i < 8; ++i) {
            int m = m0 + r0 + i;
            int bb = m >> 4, tl = m & 15;
            size_t row = (size_t)bb * T_ + t0 + tl;
            float4 v0, v1;
            v0.x = acc[i][0] + b0.x; v0.y = acc[i][1] + b0.y;
            v0.z = acc[i][2] + b0.z; v0.w = acc[i][3] + b0.w;
            v1.x = acc[i][4] + b1.x; v1.y = acc[i][5] + b1.y;
            v1.z = acc[i][6] + b1.z; v1.w = acc[i][7] + b1.w;
            *(float4*)&X[row*NCOL + n0]     = v0;
            *(float4*)&X[row*NCOL + n0 + 4] = v1;
        }
    }
}

// ---------------------------------------------------------------------------
// Phase 2: full recurrence, SINGLE launch, grid=256 x 512 threads.
// BYTE-EXACT R13 (565 us verified). Do not edit — see header comment.
// ---------------------------------------------------------------------------
__global__ __launch_bounds__(512, 2) void recur_kernel(
    const float* __restrict__ X, const uint4* __restrict__ U8,
    const uint4* __restrict__ UF,
    const float* __restrict__ U_a, const float* __restrict__ b_a,
    const float* __restrict__ W_p, const float* __restrict__ b_p,
    const float* __restrict__ fc_w, const float* __restrict__ fc_b,
    float* __restrict__ out)
{
    __shared__ uint4 ldsU[NLDS * 1024];  // 147,456 B
    __shared__ float pre_s[1024];        //   4,096 B
    __shared__ uint4 h_p4[H_/8];         //     512 B (h as fp16 pairs)
    __shared__ float qp[64];             //     256 B (fre quarter partials: [fcol][q])
    __shared__ float cs_s[16], sn_s[16]; //     128 B   (total ~152.4 KB)

    int tid  = threadIdx.x;
    int b    = blockIdx.x;
    int lane = tid & 63;
    int wid  = tid >> 6;                 // 0..7

    int c0 = tid;                        // column pair owned by this thread
    int c1 = tid + 512;

    // fre ownership: designated lanes (lane&7)==7, 8 per wave.
    // lane -> quarter q = lane>>4 (0..3), colsel = (lane>>3)&1;
    // fre col fcol = wid + 8*colsel (0..15).
    bool isfre = ((lane & 7) == 7);
    int fq     = lane >> 4;
    int fcol   = wid + 8 * ((lane >> 3) & 1);

    // update-phase ownership: j = tid>>1 (h row), f0 = (tid&1)*8 (8 freqs)
    int j     = tid >> 1;
    int fhalf = tid & 1;
    int f0    = fhalf * 8;

    // stage LDS U tier (slots 0..NLDS-1)
    for (int i = tid; i < NLDS * 1024; i += 512)
        ldsU[i] = U8[i];

    // persistent register U tier (slots NLDS..NLDS+NREG-1), loaded once.
    // Fully-static indexing only (rule #20).
    uint4 ur0[NREG], ur1[NREG];
    #pragma unroll
    for (int r = 0; r < NREG; ++r) {
        ur0[r] = U8[(NLDS + r) * 1024 + c0];
        ur1[r] = U8[(NLDS + r) * 1024 + c1];
    }

    if (tid < H_/8) { uint4 z; z.x=z.y=z.z=z.w=0u; h_p4[tid] = z; }
    if (tid < 16) {
        float ang = (float)tid * 0.39269908169872414f; // 2*pi/16
        cs_s[tid] = cosf(ang);
        sn_s[tid] = sinf(ang);
    }
    float Sre[8], Sim[8];
    #pragma unroll
    for (int r = 0; r < 8; ++r) { Sre[r] = 0.0f; Sim[r] = 0.0f; }

    float ba_j = b_a[j];
    float4 ua4a = ((const float4*)U_a)[fhalf * 2 + 0];
    float4 ua4b = ((const float4*)U_a)[fhalf * 2 + 1];
    const uint4* UFq = UF + (fcol * 32 + fq * 8);   // quarter fq of fre col fcol
    const float* Xb = X + (size_t)b * T_ * NCOL;
    __half* h_h = (__half*)h_p4;

    float hnew = 0.0f;
    __syncthreads();

    for (int t = 0; t < T_; ++t) {
        const float* xrow = Xb + (size_t)t * NCOL;

        // ---- dot phase: pre[c] = x[c] + U[:,c] . h for c in {c0, c1} ----
        float a0 = ntload_f(&xrow[c0]);
        float a1 = ntload_f(&xrow[c1]);
        // streamed tier (slots NSTR0..31): loads pipeline across lbar()
        #pragma unroll
        for (int kk = NSTR0; kk < 32; ++kk) {
            uint4 u0 = U8[kk * 1024 + c0];
            uint4 u1 = U8[kk * 1024 + c1];
            uint4 hh = h_p4[kk];
            a0 = dot2x4(u0, hh, a0);
            a1 = dot2x4(u1, hh, a1);
        }
        // register tier (slots NLDS..NSTR0-1)
        #pragma unroll
        for (int r = 0; r < NREG; ++r) {
            uint4 hh = h_p4[NLDS + r];
            a0 = dot2x4(ur0[r], hh, a0);
            a1 = dot2x4(ur1[r], hh, a1);
        }
        // LDS tier (slots 0..NLDS-1); h_p4 reads are broadcasts
        #pragma unroll
        for (int d = 0; d < NLDS; ++d) {
            uint4 u0 = ldsU[d * 1024 + c0];
            uint4 u1 = ldsU[d * 1024 + c1];
            uint4 hh = h_p4[d];
            a0 = dot2x4(u0, hh, a0);
            a1 = dot2x4(u1, hh, a1);
        }
        float fa = 0.0f;
        if (isfre) {
            #pragma unroll
            for (int s = 0; s < 8; ++s)
                fa = dot2x4(UFq[s], h_p4[fq * 8 + s], fa);
        }
        pre_s[c0] = a0;
        pre_s[c1] = a1;
        if (isfre) qp[fcol * 4 + fq] = fa;
        lbar();   // A: pre_s + qp visible; h_p4 reads done (lgkm only)

        // ---- update phase ----
        float xi   = pre_s[j];
        float xste = pre_s[256 + j];
        float xc   = pre_s[512 + j];
        float xo   = pre_s[768 + j];
        float gi   = hsig(xi);
        float gste = hsig(xste);
        float go   = hsig(xo);
        float cc   = gi * tanhf(xc);

        float4 xfa = ntload_f4(&xrow[1024 + f0]);
        float4 xfb = ntload_f4(&xrow[1024 + f0 + 4]);
        float xfre[8] = {xfa.x, xfa.y, xfa.z, xfa.w, xfb.x, xfb.y, xfb.z, xfb.w};
        float fre[8];
        #pragma unroll
        for (int r = 0; r < 8; ++r) {
            float4 q = *(const float4*)&qp[(f0 + r) * 4];
            fre[r] = hsig(xfre[r] + q.x + q.y + q.z + q.w);
        }

        int tt1 = (t + 1) & 15;
        float ua[8] = {ua4a.x, ua4a.y, ua4a.z, ua4a.w, ua4b.x, ua4b.y, ua4b.z, ua4b.w};
        float Aa = 0.0f;
        #pragma unroll
        for (int r = 0; r < 8; ++r) {
            int idx = (tt1 * (f0 + r)) & 15;
            float dec = gste * fre[r];
            float sre = fmaf(dec, Sre[r], cc * cs_s[idx]);
            float sim = fmaf(dec, Sim[r], cc * sn_s[idx]);
            Sre[r] = sre; Sim[r] = sim;
            Aa = fmaf(fmaf(sre, sre, sim*sim), ua[r], Aa);
        }
        Aa += __shfl_xor(Aa, 1);   // pair (fhalf 0/1) -> full 16-f sum
        float a = tanhf(Aa + ba_j);
        hnew = go * a;
        if (fhalf == 0) h_h[j] = __float2half(hnew);
        lbar();   // B: h visible for next step (lgkm only)
    }

    // ---- head: out[b] = (sum_j h[j]*W_p[j] + b_p)*fc_w + fc_b ----
    if (fhalf == 0) pre_s[j] = hnew * W_p[j];
    __syncthreads();
    for (int s = 128; s > 0; s >>= 1) {
        if (tid < s) pre_s[tid] += pre_s[tid + s];
        __syncthreads();
    }
    if (tid == 0) out[b] = (pre_s[0] + b_p[0]) * fc_w[0] + fc_b[0];
}

// ---------------------------------------------------------------------------
extern "C" void kernel_launch(void* const* d_in, const int* in_sizes, int n_in,
                              void* d_out, int out_size, void* d_ws, size_t ws_size,
                              hipStream_t stream) {
    const float* signal = (const float*)d_in[0];
    const float* metmast = (const float*)d_in[1];
    const float* W_i_s   = (const float*)d_in[2];
    const float* W_ste_s = (const float*)d_in[3];
    const float* W_fre_s = (const float*)d_in[4];
    const float* W_c_s   = (const float*)d_in[5];
    const float* W_o_s   = (const float*)d_in[6];
    const float* W_i_m   = (const float*)d_in[7];
    const float* W_ste_m = (const float*)d_in[8];
    const float* W_fre_m = (const float*)d_in[9];
    const float* W_c_m   = (const float*)d_in[10];
    const float* W_o_m   = (const float*)d_in[11];
    const float* U_i   = (const float*)d_in[12];
    const float* b_i   = (const float*)d_in[13];
    const float* U_ste = (const float*)d_in[14];
    const float* b_ste = (const float*)d_in[15];
    const float* U_fre = (const float*)d_in[16];
    const float* b_fre = (const float*)d_in[17];
    const float* U_c   = (const float*)d_in[18];
    const float* b_c   = (const float*)d_in[19];
    const float* U_o   = (const float*)d_in[20];
    const float* b_o   = (const float*)d_in[21];
    const float* U_a   = (const float*)d_in[22];
    const float* b_a   = (const float*)d_in[23];
    const float* W_p   = (const float*)d_in[24];
    const float* b_p   = (const float*)d_in[25];
    const float* fc_w  = (const float*)d_in[26];
    const float* fc_b  = (const float*)d_in[27];
    float* out = (float*)d_out;

    char* ws = (char*)d_ws;
    float*          Wcat = (float*)(ws + 0);                 //  96*1040*4 = 399360
    float*          bcat = (float*)(ws + 399360);            //  4160 -> 403520
    unsigned short* U8   = (unsigned short*)(ws + 403520);   //  1024*256*2 = 524288 -> 927808
    unsigned short* UF   = (unsigned short*)(ws + 927808);   //  16*256*2 = 8192 -> 936000
    float*          X    = (float*)(ws + 936000);            //  256*128*1040*4 = 136314880
    // total ~137.3 MB

    pack_kernel<<<256, 256, 0, stream>>>(
        W_i_s, W_ste_s, W_fre_s, W_c_s, W_o_s,
        W_i_m, W_ste_m, W_fre_m, W_c_m, W_o_m,
        U_i, U_ste, U_fre, U_c, U_o,
        b_i, b_ste, b_fre, b_c, b_o,
        Wcat, bcat, U8, UF);

    proj_kernel<<<dim3(9, 32, 8), 256, 0, stream>>>(signal, metmast, Wcat, bcat, X);

    recur_kernel<<<B_, 512, 0, stream>>>(X, (const uint4*)U8, (const uint4*)UF,
                                         U_a, b_a, W_p, b_p, fc_w, fc_b, out);
}